// Round 2
// baseline (437.055 us; speedup 1.0000x reference)
//
#include <hip/hip_runtime.h>

#define HW 3136
#define NPOS 12845056   // 16*256*3136

__device__ __forceinline__ unsigned fkey(float f) {
  unsigned u = __float_as_uint(f);
  return (u & 0x80000000u) ? ~u : (u | 0x80000000u);
}
__device__ __forceinline__ float funkey(unsigned u) {
  return __uint_as_float((u & 0x80000000u) ? (u & 0x7FFFFFFFu) : ~u);
}
__device__ __forceinline__ float spikef(float x) {
  return fminf(fmaxf(rintf(x), 0.0f), 4.0f);
}

// ---------------- Kernel 1: transposes + audio pre-projection + init ----------------
__global__ __launch_bounds__(256) void prep_kernel(
    const float* __restrict__ audio, const float* __restrict__ w1,
    const float* __restrict__ b1, const float* __restrict__ w2,
    float* __restrict__ a_pre, float* __restrict__ w1t,
    float* __restrict__ w2t, float* __restrict__ pool,
    unsigned* __restrict__ mm)
{
  int gid = blockIdx.x * 256 + threadIdx.x;   // 80 blocks -> 20480 threads
  // w1 visual half, transposed: w1t[c][j] = w1[j][c]
  for (int idx = gid; idx < 32768; idx += 20480) {
    int c = idx >> 7, j = idx & 127;
    w1t[idx] = w1[j * 512 + c];
  }
  // w2 transposed: w2t[k][j2] = w2[j2][k]
  if (gid < 8192) {
    int k = gid >> 6, j2 = gid & 63;
    w2t[gid] = w2[j2 * 128 + k];
  }
  if (gid < 4096) pool[gid] = 0.0f;
  if (gid == 0) { mm[0] = 0xFFFFFFFFu; mm[1] = 0u; }
  // audio pre-projection: a_pre[b][j] = b1[j] + sum_c w1[j][256+c]*audio[b][c]
  if (gid < 2048) {
    int b = gid >> 7, j = gid & 127;
    const float* wr = w1 + j * 512 + 256;
    const float* av = audio + b * 256;
    float s = 0.f;
    for (int c = 0; c < 256; ++c) s = fmaf(wr[c], av[c], s);
    a_pre[gid] = s + b1[j];
  }
}

// ---------------- Kernel 2: fused MLP + mi + pooling ----------------
// block = 128 threads (2 waves), 64 positions per block; thread = 1 position.
// Weights streamed via wave-uniform scalar loads (SGPR operand of v_fmac).
__global__ __launch_bounds__(128) void mlp_kernel(
    const float* __restrict__ fm, const float* __restrict__ w1t,
    const float* __restrict__ w2t, const float* __restrict__ b2,
    const float* __restrict__ w3, const float* __restrict__ b3,
    const float* __restrict__ g1, const float* __restrict__ be1,
    const float* __restrict__ g2, const float* __restrict__ be2,
    const float* __restrict__ a_pre, float* __restrict__ mi_out,
    float* __restrict__ pool, unsigned* __restrict__ mm)
{
  __shared__ float h1lds[128][64];   // 32 KB, stride 64 -> 2-way (free)
  __shared__ float red[2][64];
  __shared__ float red2[2][64];
  __shared__ float milds[64];

  const int b  = blockIdx.y;
  const int s0 = blockIdx.x * 64;
  const int t  = threadIdx.x;
  const int l  = t & 63;
  const int wv = __builtin_amdgcn_readfirstlane(t >> 6);  // force wave-uniform

  const size_t fm_base = (size_t)b * 256 * HW;
  const float* fmp = fm + fm_base + s0 + l;

  // ---- GEMM1: j-split across waves; acc[j] over all 256 channels ----
  float acc[64];
  #pragma unroll
  for (int j = 0; j < 64; ++j) acc[j] = 0.f;

  float xv = fmp[0];
  for (int c = 0; c < 256; ++c) {
    const float* wr = w1t + c * 128 + wv * 64;       // uniform -> s_load
    float xn = (c < 255) ? fmp[(size_t)(c + 1) * HW] : 0.f;
    #pragma unroll
    for (int j = 0; j < 64; ++j) acc[j] = fmaf(xv, wr[j], acc[j]);
    xv = xn;
  }
  {
    const float* ap = a_pre + b * 128 + wv * 64;     // uniform broadcast
    #pragma unroll
    for (int j = 0; j < 64; ++j) acc[j] += ap[j];
  }

  // ---- LN1 (two-pass) + spike, 2-float cross-wave exchange ----
  float s = 0.f;
  #pragma unroll
  for (int j = 0; j < 64; ++j) s += acc[j];
  red[wv][l] = s;
  __syncthreads();
  float mu = (red[0][l] + red[1][l]) * (1.0f / 128.0f);
  float s2 = 0.f;
  #pragma unroll
  for (int j = 0; j < 64; ++j) { float d = acc[j] - mu; s2 = fmaf(d, d, s2); }
  red2[wv][l] = s2;
  __syncthreads();
  float var = (red2[0][l] + red2[1][l]) * (1.0f / 128.0f);
  float inv = 1.0f / sqrtf(var + 1e-5f);
  {
    const float* g  = g1  + wv * 64;
    const float* be = be1 + wv * 64;
    #pragma unroll
    for (int j = 0; j < 64; ++j)
      h1lds[wv * 64 + j][l] = spikef((acc[j] - mu) * inv * g[j] + be[j]);
  }
  __syncthreads();

  // ---- GEMM2: k-split across waves; w2 via scalar loads ----
  float acc2[64];
  #pragma unroll
  for (int j = 0; j < 64; ++j) acc2[j] = 0.f;
  for (int kk = 0; kk < 64; ++kk) {
    int k = wv * 64 + kk;                            // uniform
    float xh = h1lds[k][l];                          // 1 b32 per 64 FMA
    const float* wr = w2t + k * 64;                  // uniform -> s_load
    #pragma unroll
    for (int j = 0; j < 64; ++j) acc2[j] = fmaf(xh, wr[j], acc2[j]);
  }
  __syncthreads();
  float (*comb)[64] = (float(*)[64])h1lds;           // reuse LDS
  if (wv == 1) {
    #pragma unroll
    for (int j = 0; j < 64; ++j) comb[j][l] = acc2[j];
  }
  __syncthreads();

  // ---- LN2 + spike + mi (wave 0 only, fully in registers) ----
  if (wv == 0) {
    float h2[64];
    float sm = 0.f;
    #pragma unroll
    for (int j = 0; j < 64; ++j) {
      h2[j] = acc2[j] + comb[j][l] + b2[j];
      sm += h2[j];
    }
    float mu2 = sm * (1.0f / 64.0f);
    float v2 = 0.f;
    #pragma unroll
    for (int j = 0; j < 64; ++j) { float d = h2[j] - mu2; v2 = fmaf(d, d, v2); }
    float inv2 = 1.0f / sqrtf(v2 * (1.0f / 64.0f) + 1e-5f);
    float mi = b3[0];
    #pragma unroll
    for (int j = 0; j < 64; ++j) {
      float p = spikef((h2[j] - mu2) * inv2 * g2[j] + be2[j]);
      mi = fmaf(p, w3[j], mi);
    }
    mi_out[b * HW + s0 + l] = mi;
    milds[l] = mi;
    float mn = mi, mx = mi;
    #pragma unroll
    for (int off = 32; off; off >>= 1) {
      mn = fminf(mn, __shfl_xor(mn, off));
      mx = fmaxf(mx, __shfl_xor(mx, off));
    }
    if (l == 0) {
      unsigned kmn = fkey(mn), kmx = fkey(mx);
      volatile unsigned* vmm = (volatile unsigned*)mm;
      if (kmn < vmm[0]) atomicMin(&mm[0], kmn);   // guard: mm only improves
      if (kmx > vmm[1]) atomicMax(&mm[1], kmx);
    }
  }
  __syncthreads();

  // ---- pooling: pool[b][c] += sum_pos mi[pos]*fm[b][c][pos] ----
  float miv = milds[l];
  for (int ci = 0; ci < 128; ++ci) {
    int c = (wv << 7) + ci;
    float v = fmp[(size_t)c * HW] * miv;
    #pragma unroll
    for (int off = 32; off; off >>= 1) v += __shfl_xor(v, off);
    if (l == 0) atomicAdd(&pool[b * 256 + c], v);
  }
}

// ---------------- Kernel 3: projection + LN + spike -> channel scale ----------------
__global__ __launch_bounds__(256) void scale_kernel(
    const float* __restrict__ pool, const float* __restrict__ pw,
    const float* __restrict__ pb, const float* __restrict__ pg,
    const float* __restrict__ pbeta, float* __restrict__ scale,
    const unsigned* __restrict__ mm, float* __restrict__ gpar)
{
  __shared__ float pl[256];
  __shared__ float xsh[256];
  __shared__ float rs[4], rs2[4];
  int b = blockIdx.x, t = threadIdx.x;
  pl[t] = pool[b*256 + t];
  __syncthreads();
  int w = t >> 6, l = t & 63;
  float p0 = pl[l], p1 = pl[l+64], p2 = pl[l+128], p3 = pl[l+192];
  for (int jj = 0; jj < 64; ++jj) {
    int j = w*64 + jj;
    const float* row = pw + j*256;
    float s = row[l]*p0 + row[l+64]*p1 + row[l+128]*p2 + row[l+192]*p3;
    #pragma unroll
    for (int off = 32; off; off >>= 1) s += __shfl_xor(s, off);
    if (l == 0) xsh[j] = s;
  }
  __syncthreads();
  float x = xsh[t] + pb[t];
  float s = x;
  #pragma unroll
  for (int off = 32; off; off >>= 1) s += __shfl_xor(s, off);
  if (l == 0) rs[w] = s;
  __syncthreads();
  float mu = (rs[0]+rs[1]+rs[2]+rs[3]) * (1.0f/256.0f);
  float d = x - mu;
  float s2 = d*d;
  #pragma unroll
  for (int off = 32; off; off >>= 1) s2 += __shfl_xor(s2, off);
  if (l == 0) rs2[w] = s2;
  __syncthreads();
  float var = (rs2[0]+rs2[1]+rs2[2]+rs2[3]) * (1.0f/256.0f);
  float v = d / sqrtf(var + 1e-5f) * pg[t] + pbeta[t];
  scale[b*256 + t] = spikef(v);
  if (b == 0 && t == 0) {
    float mn = funkey(mm[0]), mx = funkey(mm[1]);
    gpar[0] = mn;
    gpar[1] = mx - mn + 1e-6f;
  }
}

// ---------------- Kernel 4: fusion map + normalized mi map ----------------
__global__ __launch_bounds__(256) void fuse_kernel(
    const float4* __restrict__ fm4, const float* __restrict__ scale,
    const float4* __restrict__ mi4, const float* __restrict__ gpar,
    float4* __restrict__ out4, float4* __restrict__ mi4out)
{
  int bid = blockIdx.x;
  if (bid < 12544) {
    int idx = bid*256 + (int)threadIdx.x;
    int row = idx / 784;               // (b*256+c); 784 float4 per spatial row
    float s = scale[row];
    float4 v = fm4[idx];
    out4[idx] = make_float4(v.x*s, v.y*s, v.z*s, v.w*s);
  } else {
    int idx = (bid - 12544)*256 + (int)threadIdx.x;   // 12544 float4 of mi
    float gmin = gpar[0], den = gpar[1];
    float4 v = mi4[idx];
    mi4out[idx] = make_float4((v.x-gmin)/den, (v.y-gmin)/den,
                              (v.z-gmin)/den, (v.w-gmin)/den);
  }
}

extern "C" void kernel_launch(void* const* d_in, const int* in_sizes, int n_in,
                              void* d_out, int out_size, void* d_ws, size_t ws_size,
                              hipStream_t stream)
{
  const float* fm    = (const float*)d_in[0];
  const float* audio = (const float*)d_in[1];
  const float* w1    = (const float*)d_in[2];
  const float* b1    = (const float*)d_in[3];
  const float* g1    = (const float*)d_in[4];
  const float* be1   = (const float*)d_in[5];
  const float* w2    = (const float*)d_in[6];
  const float* b2    = (const float*)d_in[7];
  const float* g2    = (const float*)d_in[8];
  const float* be2   = (const float*)d_in[9];
  const float* w3    = (const float*)d_in[10];
  const float* b3    = (const float*)d_in[11];
  const float* pw    = (const float*)d_in[12];
  const float* pb    = (const float*)d_in[13];
  const float* pg    = (const float*)d_in[14];
  const float* pbeta = (const float*)d_in[15];

  float* ws    = (float*)d_ws;
  float* a_pre = ws;               // 2048 floats
  float* pool  = ws + 2048;        // 4096
  float* scale = ws + 6144;        // 4096
  float* mi    = ws + 10240;       // 50176 (16B aligned)
  float* w1t   = ws + 60416;       // 32768
  float* w2t   = ws + 93184;       // 8192
  unsigned* mm = (unsigned*)(ws + 101376);  // 2 keys
  float* gpar  = ws + 101378;      // gmin, denom

  float* out    = (float*)d_out;
  float* mi4out = out + NPOS;

  prep_kernel<<<80, 256, 0, stream>>>(audio, w1, b1, w2, a_pre, w1t, w2t,
                                      pool, mm);
  mlp_kernel<<<dim3(49, 16), 128, 0, stream>>>(fm, w1t, w2t, b2, w3, b3,
                                               g1, be1, g2, be2,
                                               a_pre, mi, pool, mm);
  scale_kernel<<<16, 256, 0, stream>>>(pool, pw, pb, pg, pbeta, scale, mm, gpar);
  fuse_kernel<<<12593, 256, 0, stream>>>((const float4*)fm, scale,
                                         (const float4*)mi, gpar,
                                         (float4*)out, (float4*)mi4out);
}

// Round 3
// 372.154 us; speedup vs baseline: 1.1744x; 1.1744x over previous
//
#include <hip/hip_runtime.h>

#define HW 3136
#define NPOS 12845056   // 16*256*3136

__device__ __forceinline__ unsigned fkey(float f) {
  unsigned u = __float_as_uint(f);
  return (u & 0x80000000u) ? ~u : (u | 0x80000000u);
}
__device__ __forceinline__ float funkey(unsigned u) {
  return __uint_as_float((u & 0x80000000u) ? (u & 0x7FFFFFFFu) : ~u);
}
__device__ __forceinline__ float spikef(float x) {
  return fminf(fmaxf(rintf(x), 0.0f), 4.0f);
}

// ---------------- Kernel 1: transposes + audio pre-projection + init ----------------
// grid 177 blocks x 256
__global__ __launch_bounds__(256) void prep_kernel(
    const float* __restrict__ audio, const float* __restrict__ w1,
    const float* __restrict__ b1, const float* __restrict__ w2,
    float* __restrict__ a_pre, float* __restrict__ w1t,
    float* __restrict__ w2t, float* __restrict__ pool,
    unsigned* __restrict__ mm)
{
  __shared__ float au[256];
  const int bx = blockIdx.x, t = threadIdx.x;
  if (bx < 128) {                       // w1 visual half -> w1t[c][j], coalesced write
    int idx = bx * 256 + t;             // 32768
    int c = idx >> 7, j = idx & 127;
    w1t[idx] = w1[j * 512 + c];
  } else if (bx < 160) {                // w2 -> w2t[k][j2], coalesced write
    int idx = (bx - 128) * 256 + t;     // 8192
    int k = idx >> 6, j2 = idx & 63;
    w2t[idx] = w2[j2 * 128 + k];
  } else if (bx < 176) {                // a_pre[b][j] = b1[j] + w1[j][256:512].audio[b]
    int b = bx - 160;
    au[t] = audio[b * 256 + t];
    __syncthreads();
    int w = t >> 6, l = t & 63;
    float a0 = au[l], a1 = au[l + 64], a2 = au[l + 128], a3 = au[l + 192];
    for (int jj = 0; jj < 32; ++jj) {
      int j = w * 32 + jj;
      const float* row = w1 + j * 512 + 256;
      float s = row[l] * a0 + row[l + 64] * a1 + row[l + 128] * a2 + row[l + 192] * a3;
      #pragma unroll
      for (int off = 32; off; off >>= 1) s += __shfl_xor(s, off);
      if (l == 0) a_pre[b * 128 + j] = s + b1[j];
    }
  } else {                              // init pool + minmax keys
    for (int i = t; i < 4096; i += 256) pool[i] = 0.0f;
    if (t == 0) { mm[0] = 0xFFFFFFFFu; mm[1] = 0u; }
  }
}

// ---------------- Kernel 2: fused MLP + mi + pooling ----------------
// 256 threads = 4 waves; lane = position (64 pos/block); wave = j-quarter.
// Weights via wave-uniform scalar loads (SGPR). fm via 16-deep register prefetch.
__global__ __launch_bounds__(256, 4) void mlp_kernel(
    const float* __restrict__ fm, const float* __restrict__ w1t,
    const float* __restrict__ w2t, const float* __restrict__ b2,
    const float* __restrict__ w3, const float* __restrict__ b3,
    const float* __restrict__ g1, const float* __restrict__ be1,
    const float* __restrict__ g2, const float* __restrict__ be2,
    const float* __restrict__ a_pre, float* __restrict__ mi_out,
    float* __restrict__ pool, unsigned* __restrict__ mm)
{
  __shared__ unsigned pk[32 * 64];     // h1 spikes packed 4-per-u32: 8 KB
  __shared__ float red1[4][64];
  __shared__ float red2[4][64];
  __shared__ float miL[64];

  const int b  = blockIdx.y;
  const int s0 = blockIdx.x * 64;
  const int t  = threadIdx.x;
  const int l  = t & 63;
  const int w  = __builtin_amdgcn_readfirstlane(t >> 6);

  const float* fmp = fm + (size_t)b * 256 * HW + s0 + l;

  // ---- GEMM1: acc[32] = j-quarter, all 256 channels ----
  float acc[32];
  #pragma unroll
  for (int j = 0; j < 32; ++j) acc[j] = 0.f;

  float xvA[16], xvB[16];
  #pragma unroll
  for (int i = 0; i < 16; ++i) xvA[i] = fmp[(size_t)i * HW];

  const float* wq = w1t + w * 32;      // uniform -> scalar loads

  auto stage = [&](int s, float (&xc)[16], float (&xn)[16]) {
    if (s < 15) {                      // issue next stage's 16 fm loads early
      #pragma unroll
      for (int i = 0; i < 16; ++i)
        xn[i] = fmp[(size_t)((s + 1) * 16 + i) * HW];
    }
    #pragma unroll
    for (int cl = 0; cl < 16; ++cl) {
      const float* wr = wq + (s * 16 + cl) * 128;   // 32 floats -> 2x s_load_dwordx16
      float x = xc[cl];
      #pragma unroll
      for (int j = 0; j < 32; ++j) acc[j] = fmaf(x, wr[j], acc[j]);
    }
  };
  #pragma unroll 1
  for (int sp = 0; sp < 8; ++sp) {
    stage(sp * 2,     xvA, xvB);
    stage(sp * 2 + 1, xvB, xvA);
  }
  {
    const float* ap = a_pre + b * 128 + w * 32;     // uniform broadcast
    #pragma unroll
    for (int j = 0; j < 32; ++j) acc[j] += ap[j];
  }

  // ---- LN1 (two-pass) + spike + pack ----
  float s1 = 0.f;
  #pragma unroll
  for (int j = 0; j < 32; ++j) s1 += acc[j];
  red1[w][l] = s1;
  __syncthreads();
  float mu = (red1[0][l] + red1[1][l] + red1[2][l] + red1[3][l]) * (1.0f / 128.0f);
  float s2 = 0.f;
  #pragma unroll
  for (int j = 0; j < 32; ++j) { float d = acc[j] - mu; s2 = fmaf(d, d, s2); }
  red2[w][l] = s2;
  __syncthreads();
  float var = (red2[0][l] + red2[1][l] + red2[2][l] + red2[3][l]) * (1.0f / 128.0f);
  float inv = 1.0f / sqrtf(var + 1e-5f);
  {
    const float* g1q  = g1  + w * 32;
    const float* be1q = be1 + w * 32;
    #pragma unroll
    for (int q = 0; q < 8; ++q) {
      unsigned u = 0;
      #pragma unroll
      for (int bb = 0; bb < 4; ++bb) {
        int j = q * 4 + bb;
        float v = spikef((acc[j] - mu) * inv * g1q[j] + be1q[j]);
        u |= ((unsigned)v) << (8 * bb);
      }
      pk[(w * 8 + q) * 64 + l] = u;   // lane-stride-1: conflict-free
    }
  }
  __syncthreads();

  // ---- GEMM2: acc2[16] = j-quarter of 64, full k=128 from packed LDS ----
  float acc2[16];
  #pragma unroll
  for (int j = 0; j < 16; ++j) acc2[j] = 0.f;
  const float* w2q = w2t + w * 16;     // uniform -> scalar loads
  #pragma unroll 4
  for (int kg = 0; kg < 32; ++kg) {
    unsigned u = pk[kg * 64 + l];
    float h0 = (float)(u & 255u);
    float h1 = (float)((u >> 8) & 255u);
    float h2 = (float)((u >> 16) & 255u);
    float h3 = (float)((u >> 24) & 255u);
    const float* wr0 = w2q + (kg * 4 + 0) * 64;
    const float* wr1 = w2q + (kg * 4 + 1) * 64;
    const float* wr2 = w2q + (kg * 4 + 2) * 64;
    const float* wr3 = w2q + (kg * 4 + 3) * 64;
    #pragma unroll
    for (int j = 0; j < 16; ++j) {
      float a = acc2[j];
      a = fmaf(h0, wr0[j], a);
      a = fmaf(h1, wr1[j], a);
      a = fmaf(h2, wr2[j], a);
      a = fmaf(h3, wr3[j], a);
      acc2[j] = a;
    }
  }

  // ---- LN2 + spike + mi ----
  float h2a[16];
  {
    const float* b2q = b2 + w * 16;
    float sm = 0.f;
    #pragma unroll
    for (int j = 0; j < 16; ++j) { h2a[j] = acc2[j] + b2q[j]; sm += h2a[j]; }
    red1[w][l] = sm;
  }
  __syncthreads();
  float mu2 = (red1[0][l] + red1[1][l] + red1[2][l] + red1[3][l]) * (1.0f / 64.0f);
  float v2 = 0.f;
  #pragma unroll
  for (int j = 0; j < 16; ++j) { float d = h2a[j] - mu2; v2 = fmaf(d, d, v2); }
  red2[w][l] = v2;
  __syncthreads();
  float var2 = (red2[0][l] + red2[1][l] + red2[2][l] + red2[3][l]) * (1.0f / 64.0f);
  float inv2 = 1.0f / sqrtf(var2 + 1e-5f);
  float mip = 0.f;
  {
    const float* g2q  = g2  + w * 16;
    const float* be2q = be2 + w * 16;
    const float* w3q  = w3  + w * 16;
    #pragma unroll
    for (int j = 0; j < 16; ++j) {
      float p = spikef((h2a[j] - mu2) * inv2 * g2q[j] + be2q[j]);
      mip = fmaf(p, w3q[j], mip);
    }
  }
  red1[w][l] = mip;     // safe: all red1 readers passed the red2 barrier
  __syncthreads();
  float mi = red1[0][l] + red1[1][l] + red1[2][l] + red1[3][l] + b3[0];
  if (w == 0) {
    mi_out[b * HW + s0 + l] = mi;
    miL[l] = mi;
    float mn = mi, mx = mi;
    #pragma unroll
    for (int off = 32; off; off >>= 1) {
      mn = fminf(mn, __shfl_xor(mn, off));
      mx = fmaxf(mx, __shfl_xor(mx, off));
    }
    if (l == 0) {
      unsigned kmn = fkey(mn), kmx = fkey(mx);
      volatile unsigned* vmm = (volatile unsigned*)mm;
      if (kmn < vmm[0]) atomicMin(&mm[0], kmn);
      if (kmx > vmm[1]) atomicMax(&mm[1], kmx);
    }
  }
  __syncthreads();

  // ---- pooling: pool[b][c] += sum_pos mi[pos]*fm[b][c][pos] ----
  const float miv = miL[l];
  #pragma unroll 4
  for (int ci = 0; ci < 64; ++ci) {
    int c = (w << 6) + ci;
    float v = fmp[(size_t)c * HW] * miv;
    #pragma unroll
    for (int off = 32; off; off >>= 1) v += __shfl_xor(v, off);
    if (l == 0) atomicAdd(&pool[b * 256 + c], v);
  }
}

// ---------------- Kernel 3: projection + LN + spike -> channel scale ----------------
__global__ __launch_bounds__(256) void scale_kernel(
    const float* __restrict__ pool, const float* __restrict__ pw,
    const float* __restrict__ pb, const float* __restrict__ pg,
    const float* __restrict__ pbeta, float* __restrict__ scale,
    const unsigned* __restrict__ mm, float* __restrict__ gpar)
{
  __shared__ float pl[256];
  __shared__ float xsh[256];
  __shared__ float rs[4], rs2[4];
  int b = blockIdx.x, t = threadIdx.x;
  pl[t] = pool[b*256 + t];
  __syncthreads();
  int w = t >> 6, l = t & 63;
  float p0 = pl[l], p1 = pl[l+64], p2 = pl[l+128], p3 = pl[l+192];
  for (int jj = 0; jj < 64; ++jj) {
    int j = w*64 + jj;
    const float* row = pw + j*256;
    float s = row[l]*p0 + row[l+64]*p1 + row[l+128]*p2 + row[l+192]*p3;
    #pragma unroll
    for (int off = 32; off; off >>= 1) s += __shfl_xor(s, off);
    if (l == 0) xsh[j] = s;
  }
  __syncthreads();
  float x = xsh[t] + pb[t];
  float s = x;
  #pragma unroll
  for (int off = 32; off; off >>= 1) s += __shfl_xor(s, off);
  if (l == 0) rs[w] = s;
  __syncthreads();
  float mu = (rs[0]+rs[1]+rs[2]+rs[3]) * (1.0f/256.0f);
  float d = x - mu;
  float s2 = d*d;
  #pragma unroll
  for (int off = 32; off; off >>= 1) s2 += __shfl_xor(s2, off);
  if (l == 0) rs2[w] = s2;
  __syncthreads();
  float var = (rs2[0]+rs2[1]+rs2[2]+rs2[3]) * (1.0f/256.0f);
  float v = d / sqrtf(var + 1e-5f) * pg[t] + pbeta[t];
  scale[b*256 + t] = spikef(v);
  if (b == 0 && t == 0) {
    float mn = funkey(mm[0]), mx = funkey(mm[1]);
    gpar[0] = mn;
    gpar[1] = mx - mn + 1e-6f;
  }
}

// ---------------- Kernel 4: fusion map + normalized mi map ----------------
// grid (257, 16): x<256 -> one (b,c) row of 784 float4; x==256 -> mi norm for b
__global__ __launch_bounds__(256) void fuse_kernel(
    const float4* __restrict__ fm4, const float* __restrict__ scale,
    const float4* __restrict__ mi4, const float* __restrict__ gpar,
    float4* __restrict__ out4, float4* __restrict__ mi4out)
{
  const int c = blockIdx.x, b = blockIdx.y, t = threadIdx.x;
  if (c < 256) {
    float s = scale[b * 256 + c];
    size_t base = ((size_t)b * 256 + c) * 784;
    #pragma unroll
    for (int i = 0; i < 3; ++i) {
      int idx = t + i * 256;
      float4 v = fm4[base + idx];
      out4[base + idx] = make_float4(v.x*s, v.y*s, v.z*s, v.w*s);
    }
    int idx = t + 768;
    if (idx < 784) {
      float4 v = fm4[base + idx];
      out4[base + idx] = make_float4(v.x*s, v.y*s, v.z*s, v.w*s);
    }
  } else {
    float gmin = gpar[0], den = gpar[1];
    size_t base = (size_t)b * 784;
    #pragma unroll
    for (int i = 0; i < 3; ++i) {
      int idx = t + i * 256;
      float4 v = mi4[base + idx];
      mi4out[base + idx] = make_float4((v.x-gmin)/den, (v.y-gmin)/den,
                                       (v.z-gmin)/den, (v.w-gmin)/den);
    }
    int idx = t + 768;
    if (idx < 784) {
      float4 v = mi4[base + idx];
      mi4out[base + idx] = make_float4((v.x-gmin)/den, (v.y-gmin)/den,
                                       (v.z-gmin)/den, (v.w-gmin)/den);
    }
  }
}

extern "C" void kernel_launch(void* const* d_in, const int* in_sizes, int n_in,
                              void* d_out, int out_size, void* d_ws, size_t ws_size,
                              hipStream_t stream)
{
  const float* fm    = (const float*)d_in[0];
  const float* audio = (const float*)d_in[1];
  const float* w1    = (const float*)d_in[2];
  const float* b1    = (const float*)d_in[3];
  const float* g1    = (const float*)d_in[4];
  const float* be1   = (const float*)d_in[5];
  const float* w2    = (const float*)d_in[6];
  const float* b2    = (const float*)d_in[7];
  const float* g2    = (const float*)d_in[8];
  const float* be2   = (const float*)d_in[9];
  const float* w3    = (const float*)d_in[10];
  const float* b3    = (const float*)d_in[11];
  const float* pw    = (const float*)d_in[12];
  const float* pb    = (const float*)d_in[13];
  const float* pg    = (const float*)d_in[14];
  const float* pbeta = (const float*)d_in[15];

  float* ws    = (float*)d_ws;
  float* a_pre = ws;               // 2048 floats
  float* pool  = ws + 2048;        // 4096
  float* scale = ws + 6144;        // 4096
  float* mi    = ws + 10240;       // 50176 (16B aligned)
  float* w1t   = ws + 60416;       // 32768  [c][j]
  float* w2t   = ws + 93184;       // 8192   [k][j2]
  unsigned* mm = (unsigned*)(ws + 101376);  // 2 keys
  float* gpar  = ws + 101378;      // gmin, denom

  float* out    = (float*)d_out;
  float* mi4out = out + NPOS;

  prep_kernel<<<177, 256, 0, stream>>>(audio, w1, b1, w2, a_pre, w1t, w2t,
                                       pool, mm);
  mlp_kernel<<<dim3(49, 16), 256, 0, stream>>>(fm, w1t, w2t, b2, w3, b3,
                                               g1, be1, g2, be2,
                                               a_pre, mi, pool, mm);
  scale_kernel<<<16, 256, 0, stream>>>(pool, pw, pb, pg, pbeta, scale, mm, gpar);
  fuse_kernel<<<dim3(257, 16), 256, 0, stream>>>((const float4*)fm, scale,
                                                 (const float4*)mi, gpar,
                                                 (float4*)out, (float4*)mi4out);
}

// Round 4
// 329.804 us; speedup vs baseline: 1.3252x; 1.1284x over previous
//
#include <hip/hip_runtime.h>

#define HW 3136
#define NPOS 12845056   // 16*256*3136

__device__ __forceinline__ unsigned fkey(float f) {
  unsigned u = __float_as_uint(f);
  return (u & 0x80000000u) ? ~u : (u | 0x80000000u);
}
__device__ __forceinline__ float funkey(unsigned u) {
  return __uint_as_float((u & 0x80000000u) ? (u & 0x7FFFFFFFu) : ~u);
}
__device__ __forceinline__ float spikef(float x) {
  return fminf(fmaxf(rintf(x), 0.0f), 4.0f);
}

// ---------------- Kernel 1: transposes + audio pre-projection + init ----------------
// grid 177 blocks x 256
__global__ __launch_bounds__(256) void prep_kernel(
    const float* __restrict__ audio, const float* __restrict__ w1,
    const float* __restrict__ b1, const float* __restrict__ w2,
    float* __restrict__ a_pre, float* __restrict__ w1t,
    float* __restrict__ w2t, float* __restrict__ pool,
    unsigned* __restrict__ mm)
{
  __shared__ float au[256];
  const int bx = blockIdx.x, t = threadIdx.x;
  if (bx < 128) {                       // w1 visual half -> w1t[c][j], coalesced write
    int idx = bx * 256 + t;             // 32768
    int c = idx >> 7, j = idx & 127;
    w1t[idx] = w1[j * 512 + c];
  } else if (bx < 160) {                // w2 -> w2t[k][j2], coalesced write
    int idx = (bx - 128) * 256 + t;     // 8192
    int k = idx >> 6, j2 = idx & 63;
    w2t[idx] = w2[j2 * 128 + k];
  } else if (bx < 176) {                // a_pre[b][j] = b1[j] + w1[j][256:512].audio[b]
    int b = bx - 160;
    au[t] = audio[b * 256 + t];
    __syncthreads();
    int w = t >> 6, l = t & 63;
    float a0 = au[l], a1 = au[l + 64], a2 = au[l + 128], a3 = au[l + 192];
    for (int jj = 0; jj < 32; ++jj) {
      int j = w * 32 + jj;
      const float* row = w1 + j * 512 + 256;
      float s = row[l] * a0 + row[l + 64] * a1 + row[l + 128] * a2 + row[l + 192] * a3;
      #pragma unroll
      for (int off = 32; off; off >>= 1) s += __shfl_xor(s, off);
      if (l == 0) a_pre[b * 128 + j] = s + b1[j];
    }
  } else {                              // init pool + minmax keys
    for (int i = t; i < 4096; i += 256) pool[i] = 0.0f;
    if (t == 0) { mm[0] = 0xFFFFFFFFu; mm[1] = 0u; }
  }
}

// ---------------- Kernel 2: fused MLP + mi + pooling ----------------
// 256 threads = 4 waves; 128 positions/block (2 per lane); wave = j-quarter.
// Weights via wave-uniform scalar loads; 2 positions per lane double the FMA
// run between dependent s_load pairs (hides scalar latency) and halve weight
// traffic per FMA. Tail tile (s0=3072) has only 64 valid positions: uniform
// has2 flag, off2=0 aliases set2 loads onto set1 (safe addresses), set2
// results masked at stores/pooling/minmax.
__global__ __launch_bounds__(256, 2) void mlp_kernel(
    const float* __restrict__ fm, const float* __restrict__ w1t,
    const float* __restrict__ w2t, const float* __restrict__ b2,
    const float* __restrict__ w3, const float* __restrict__ b3,
    const float* __restrict__ g1, const float* __restrict__ be1,
    const float* __restrict__ g2, const float* __restrict__ be2,
    const float* __restrict__ a_pre, float* __restrict__ mi_out,
    float* __restrict__ pool, unsigned* __restrict__ mm)
{
  __shared__ unsigned pk[32 * 128];    // h1 spikes packed 4-per-u32: 16 KB
  __shared__ float red1[4][128];
  __shared__ float red2[4][128];
  __shared__ float miL[128];

  const int b  = blockIdx.y;
  const int s0 = blockIdx.x * 128;
  const int t  = threadIdx.x;
  const int l  = t & 63;
  const int w  = __builtin_amdgcn_readfirstlane(t >> 6);
  const bool has2 = (s0 + 128) <= HW;
  const size_t off2 = has2 ? 64 : 0;

  const float* fmp = fm + (size_t)b * 256 * HW + s0 + l;

  // ---- GEMM1: acc[2][32] = (pos-set, j-quarter), all 256 channels ----
  float acc0[32], acc1[32];
  #pragma unroll
  for (int j = 0; j < 32; ++j) { acc0[j] = 0.f; acc1[j] = 0.f; }

  const float* wq = w1t + w * 32;      // uniform -> scalar loads

  float xa0[8], xa1[8], xb0[8], xb1[8];
  #pragma unroll
  for (int i = 0; i < 8; ++i) {
    size_t o = (size_t)i * HW;
    xa0[i] = fmp[o]; xa1[i] = fmp[o + off2];
  }

  auto stage = [&](int cbase, float (&c0)[8], float (&c1)[8],
                   float (&n0)[8], float (&n1)[8], bool pre) {
    if (pre) {                         // prefetch next 8 channels, both sets
      #pragma unroll
      for (int i = 0; i < 8; ++i) {
        size_t o = (size_t)(cbase + 8 + i) * HW;
        n0[i] = fmp[o]; n1[i] = fmp[o + off2];
      }
    }
    #pragma unroll
    for (int cl = 0; cl < 8; ++cl) {
      const float* wr = wq + (cbase + cl) * 128;  // 32 floats -> 2x s_load_dwordx16
      float x0 = c0[cl], x1 = c1[cl];
      #pragma unroll
      for (int j = 0; j < 32; ++j) {
        acc0[j] = fmaf(x0, wr[j], acc0[j]);
        acc1[j] = fmaf(x1, wr[j], acc1[j]);
      }
    }
  };
  #pragma unroll 1
  for (int sp = 0; sp < 16; ++sp) {
    stage(sp * 16,     xa0, xa1, xb0, xb1, true);
    stage(sp * 16 + 8, xb0, xb1, xa0, xa1, sp < 15);
  }
  {
    const float* ap = a_pre + b * 128 + w * 32;   // uniform broadcast
    #pragma unroll
    for (int j = 0; j < 32; ++j) { acc0[j] += ap[j]; acc1[j] += ap[j]; }
  }

  // ---- LN1 (two-pass) + spike + pack, both sets ----
  {
    float s0s = 0.f, s1s = 0.f;
    #pragma unroll
    for (int j = 0; j < 32; ++j) { s0s += acc0[j]; s1s += acc1[j]; }
    red1[w][l] = s0s; red1[w][64 + l] = s1s;
  }
  __syncthreads();
  float mu0 = (red1[0][l] + red1[1][l] + red1[2][l] + red1[3][l]) * (1.0f / 128.0f);
  float mu1 = (red1[0][64+l] + red1[1][64+l] + red1[2][64+l] + red1[3][64+l]) * (1.0f / 128.0f);
  {
    float v0 = 0.f, v1 = 0.f;
    #pragma unroll
    for (int j = 0; j < 32; ++j) {
      float d0 = acc0[j] - mu0; v0 = fmaf(d0, d0, v0);
      float d1 = acc1[j] - mu1; v1 = fmaf(d1, d1, v1);
    }
    red2[w][l] = v0; red2[w][64 + l] = v1;
  }
  __syncthreads();
  float var0 = (red2[0][l] + red2[1][l] + red2[2][l] + red2[3][l]) * (1.0f / 128.0f);
  float var1 = (red2[0][64+l] + red2[1][64+l] + red2[2][64+l] + red2[3][64+l]) * (1.0f / 128.0f);
  float inv0 = 1.0f / sqrtf(var0 + 1e-5f);
  float inv1 = 1.0f / sqrtf(var1 + 1e-5f);
  {
    const float* g1q  = g1  + w * 32;
    const float* be1q = be1 + w * 32;
    #pragma unroll
    for (int q = 0; q < 8; ++q) {
      unsigned u0 = 0, u1 = 0;
      #pragma unroll
      for (int bb = 0; bb < 4; ++bb) {
        int j = q * 4 + bb;
        float gv = g1q[j], bv = be1q[j];
        float v0 = spikef((acc0[j] - mu0) * inv0 * gv + bv);
        float v1 = spikef((acc1[j] - mu1) * inv1 * gv + bv);
        u0 |= ((unsigned)v0) << (8 * bb);
        u1 |= ((unsigned)v1) << (8 * bb);
      }
      pk[(w * 8 + q) * 128 + l]      = u0;   // lane-stride-1: conflict-free
      pk[(w * 8 + q) * 128 + 64 + l] = u1;
    }
  }
  __syncthreads();

  // ---- GEMM2: acc2[2][16], full k=128 from packed LDS ----
  float a20[16], a21[16];
  #pragma unroll
  for (int j = 0; j < 16; ++j) { a20[j] = 0.f; a21[j] = 0.f; }
  const float* w2q = w2t + w * 16;     // uniform -> scalar loads
  #pragma unroll 2
  for (int kg = 0; kg < 32; ++kg) {
    unsigned u0 = pk[kg * 128 + l];
    unsigned u1 = pk[kg * 128 + 64 + l];
    #pragma unroll
    for (int kk = 0; kk < 4; ++kk) {
      const float* wr = w2q + (kg * 4 + kk) * 64;
      float h0 = (float)((u0 >> (8 * kk)) & 255u);
      float h1 = (float)((u1 >> (8 * kk)) & 255u);
      #pragma unroll
      for (int j = 0; j < 16; ++j) {
        a20[j] = fmaf(h0, wr[j], a20[j]);
        a21[j] = fmaf(h1, wr[j], a21[j]);
      }
    }
  }

  // ---- LN2 + spike + mi, both sets ----
  float h20[16], h21[16];
  {
    const float* b2q = b2 + w * 16;
    float sm0 = 0.f, sm1 = 0.f;
    #pragma unroll
    for (int j = 0; j < 16; ++j) {
      h20[j] = a20[j] + b2q[j]; sm0 += h20[j];
      h21[j] = a21[j] + b2q[j]; sm1 += h21[j];
    }
    red1[w][l] = sm0; red1[w][64 + l] = sm1;
  }
  __syncthreads();
  float mu20 = (red1[0][l] + red1[1][l] + red1[2][l] + red1[3][l]) * (1.0f / 64.0f);
  float mu21 = (red1[0][64+l] + red1[1][64+l] + red1[2][64+l] + red1[3][64+l]) * (1.0f / 64.0f);
  {
    float v0 = 0.f, v1 = 0.f;
    #pragma unroll
    for (int j = 0; j < 16; ++j) {
      float d0 = h20[j] - mu20; v0 = fmaf(d0, d0, v0);
      float d1 = h21[j] - mu21; v1 = fmaf(d1, d1, v1);
    }
    red2[w][l] = v0; red2[w][64 + l] = v1;
  }
  __syncthreads();
  float var20 = (red2[0][l] + red2[1][l] + red2[2][l] + red2[3][l]) * (1.0f / 64.0f);
  float var21 = (red2[0][64+l] + red2[1][64+l] + red2[2][64+l] + red2[3][64+l]) * (1.0f / 64.0f);
  float inv20 = 1.0f / sqrtf(var20 + 1e-5f);
  float inv21 = 1.0f / sqrtf(var21 + 1e-5f);
  float mip0 = 0.f, mip1 = 0.f;
  {
    const float* g2q  = g2  + w * 16;
    const float* be2q = be2 + w * 16;
    const float* w3q  = w3  + w * 16;
    #pragma unroll
    for (int j = 0; j < 16; ++j) {
      float gv = g2q[j], bv = be2q[j], wv = w3q[j];
      float p0 = spikef((h20[j] - mu20) * inv20 * gv + bv);
      float p1 = spikef((h21[j] - mu21) * inv21 * gv + bv);
      mip0 = fmaf(p0, wv, mip0);
      mip1 = fmaf(p1, wv, mip1);
    }
  }
  red1[w][l] = mip0; red1[w][64 + l] = mip1;   // safe: red1 readers passed red2 barrier
  __syncthreads();
  if (w == 0) {
    float mi0 = red1[0][l] + red1[1][l] + red1[2][l] + red1[3][l] + b3[0];
    float mi1 = red1[0][64+l] + red1[1][64+l] + red1[2][64+l] + red1[3][64+l] + b3[0];
    mi_out[b * HW + s0 + l] = mi0;
    if (has2) mi_out[b * HW + s0 + 64 + l] = mi1;
    miL[l] = mi0;
    miL[64 + l] = has2 ? mi1 : 0.0f;            // 0 => no pooling contribution
    float mn = has2 ? fminf(mi0, mi1) : mi0;
    float mx = has2 ? fmaxf(mi0, mi1) : mi0;
    #pragma unroll
    for (int off = 32; off; off >>= 1) {
      mn = fminf(mn, __shfl_xor(mn, off));
      mx = fmaxf(mx, __shfl_xor(mx, off));
    }
    if (l == 0) {
      unsigned kmn = fkey(mn), kmx = fkey(mx);
      volatile unsigned* vmm = (volatile unsigned*)mm;
      if (kmn < vmm[0]) atomicMin(&mm[0], kmn);
      if (kmx > vmm[1]) atomicMax(&mm[1], kmx);
    }
  }
  __syncthreads();

  // ---- pooling: pool[b][c] += sum_pos mi[pos]*fm[b][c][pos] ----
  const float m0 = miL[l], m1 = miL[64 + l];
  #pragma unroll 4
  for (int ci = 0; ci < 64; ++ci) {
    int c = (w << 6) + ci;
    size_t o = (size_t)c * HW;
    float v = fmp[o] * m0 + fmp[o + off2] * m1;
    #pragma unroll
    for (int off = 32; off; off >>= 1) v += __shfl_xor(v, off);
    if (l == 0) atomicAdd(&pool[b * 256 + c], v);
  }
}

// ---------------- Kernel 3: projection + LN + spike -> channel scale ----------------
__global__ __launch_bounds__(256) void scale_kernel(
    const float* __restrict__ pool, const float* __restrict__ pw,
    const float* __restrict__ pb, const float* __restrict__ pg,
    const float* __restrict__ pbeta, float* __restrict__ scale,
    const unsigned* __restrict__ mm, float* __restrict__ gpar)
{
  __shared__ float pl[256];
  __shared__ float xsh[256];
  __shared__ float rs[4], rs2[4];
  int b = blockIdx.x, t = threadIdx.x;
  pl[t] = pool[b*256 + t];
  __syncthreads();
  int w = t >> 6, l = t & 63;
  float p0 = pl[l], p1 = pl[l+64], p2 = pl[l+128], p3 = pl[l+192];
  for (int jj = 0; jj < 64; ++jj) {
    int j = w*64 + jj;
    const float* row = pw + j*256;
    float s = row[l]*p0 + row[l+64]*p1 + row[l+128]*p2 + row[l+192]*p3;
    #pragma unroll
    for (int off = 32; off; off >>= 1) s += __shfl_xor(s, off);
    if (l == 0) xsh[j] = s;
  }
  __syncthreads();
  float x = xsh[t] + pb[t];
  float s = x;
  #pragma unroll
  for (int off = 32; off; off >>= 1) s += __shfl_xor(s, off);
  if (l == 0) rs[w] = s;
  __syncthreads();
  float mu = (rs[0]+rs[1]+rs[2]+rs[3]) * (1.0f/256.0f);
  float d = x - mu;
  float s2 = d*d;
  #pragma unroll
  for (int off = 32; off; off >>= 1) s2 += __shfl_xor(s2, off);
  if (l == 0) rs2[w] = s2;
  __syncthreads();
  float var = (rs2[0]+rs2[1]+rs2[2]+rs2[3]) * (1.0f/256.0f);
  float v = d / sqrtf(var + 1e-5f) * pg[t] + pbeta[t];
  scale[b*256 + t] = spikef(v);
  if (b == 0 && t == 0) {
    float mn = funkey(mm[0]), mx = funkey(mm[1]);
    gpar[0] = mn;
    gpar[1] = mx - mn + 1e-6f;
  }
}

// ---------------- Kernel 4: fusion map + normalized mi map ----------------
// grid (257, 16): x<256 -> one (b,c) row of 784 float4; x==256 -> mi norm for b
__global__ __launch_bounds__(256) void fuse_kernel(
    const float4* __restrict__ fm4, const float* __restrict__ scale,
    const float4* __restrict__ mi4, const float* __restrict__ gpar,
    float4* __restrict__ out4, float4* __restrict__ mi4out)
{
  const int c = blockIdx.x, b = blockIdx.y, t = threadIdx.x;
  if (c < 256) {
    float s = scale[b * 256 + c];
    size_t base = ((size_t)b * 256 + c) * 784;
    #pragma unroll
    for (int i = 0; i < 3; ++i) {
      int idx = t + i * 256;
      float4 v = fm4[base + idx];
      out4[base + idx] = make_float4(v.x*s, v.y*s, v.z*s, v.w*s);
    }
    int idx = t + 768;
    if (idx < 784) {
      float4 v = fm4[base + idx];
      out4[base + idx] = make_float4(v.x*s, v.y*s, v.z*s, v.w*s);
    }
  } else {
    float gmin = gpar[0], den = gpar[1];
    size_t base = (size_t)b * 784;
    #pragma unroll
    for (int i = 0; i < 3; ++i) {
      int idx = t + i * 256;
      float4 v = mi4[base + idx];
      mi4out[base + idx] = make_float4((v.x-gmin)/den, (v.y-gmin)/den,
                                       (v.z-gmin)/den, (v.w-gmin)/den);
    }
    int idx = t + 768;
    if (idx < 784) {
      float4 v = mi4[base + idx];
      mi4out[base + idx] = make_float4((v.x-gmin)/den, (v.y-gmin)/den,
                                       (v.z-gmin)/den, (v.w-gmin)/den);
    }
  }
}

extern "C" void kernel_launch(void* const* d_in, const int* in_sizes, int n_in,
                              void* d_out, int out_size, void* d_ws, size_t ws_size,
                              hipStream_t stream)
{
  const float* fm    = (const float*)d_in[0];
  const float* audio = (const float*)d_in[1];
  const float* w1    = (const float*)d_in[2];
  const float* b1    = (const float*)d_in[3];
  const float* g1    = (const float*)d_in[4];
  const float* be1   = (const float*)d_in[5];
  const float* w2    = (const float*)d_in[6];
  const float* b2    = (const float*)d_in[7];
  const float* g2    = (const float*)d_in[8];
  const float* be2   = (const float*)d_in[9];
  const float* w3    = (const float*)d_in[10];
  const float* b3    = (const float*)d_in[11];
  const float* pw    = (const float*)d_in[12];
  const float* pb    = (const float*)d_in[13];
  const float* pg    = (const float*)d_in[14];
  const float* pbeta = (const float*)d_in[15];

  float* ws    = (float*)d_ws;
  float* a_pre = ws;               // 2048 floats
  float* pool  = ws + 2048;        // 4096
  float* scale = ws + 6144;        // 4096
  float* mi    = ws + 10240;       // 50176 (16B aligned)
  float* w1t   = ws + 60416;       // 32768  [c][j]
  float* w2t   = ws + 93184;       // 8192   [k][j2]
  unsigned* mm = (unsigned*)(ws + 101376);  // 2 keys
  float* gpar  = ws + 101378;      // gmin, denom

  float* out    = (float*)d_out;
  float* mi4out = out + NPOS;

  prep_kernel<<<177, 256, 0, stream>>>(audio, w1, b1, w2, a_pre, w1t, w2t,
                                       pool, mm);
  mlp_kernel<<<dim3(25, 16), 256, 0, stream>>>(fm, w1t, w2t, b2, w3, b3,
                                               g1, be1, g2, be2,
                                               a_pre, mi, pool, mm);
  scale_kernel<<<16, 256, 0, stream>>>(pool, pw, pb, pg, pbeta, scale, mm, gpar);
  fuse_kernel<<<dim3(257, 16), 256, 0, stream>>>((const float4*)fm, scale,
                                                 (const float4*)mi, gpar,
                                                 (float4*)out, (float4*)mi4out);
}